// Round 1
// baseline (474.925 us; speedup 1.0000x reference)
//
#include <hip/hip_runtime.h>

// LIF recurrence: V = V + alpha*(V_RESET - V + I); spike = V>=1.0; V=0 on spike.
// N=65536 neurons (parallel), T=1024 steps (sequential per neuron).
// Pure HBM stream: 256 MB read + 256 MB write.

#define T_STEPS 1024
#define NUM_NEURONS 65536
#define VEC 4
#define NVEC (NUM_NEURONS / VEC)  // 16384 float4 columns per row
#define BLOCK 64                  // 1 wave per block -> 256 blocks spread over 256 CUs
#define UNROLL 16                 // 16 loads in flight per wave (16 KB/wave, 4 MB device-wide)

typedef float f4 __attribute__((ext_vector_type(4)));

__global__ __launch_bounds__(BLOCK) void lif_kernel(const f4* __restrict__ in,
                                                    f4* __restrict__ out) {
    const int gid = blockIdx.x * BLOCK + threadIdx.x;  // [0, NVEC)
    constexpr float alpha = 0.05f;   // DT/TAU = 1/20
    constexpr float vth = 1.0f;

    float vx = 0.0f, vy = 0.0f, vz = 0.0f, vw = 0.0f;  // V_RESET = 0
    const f4* __restrict__ p = in + gid;
    f4* __restrict__ q = out + gid;

    for (int t = 0; t < T_STEPS; t += UNROLL) {
        f4 I[UNROLL];
#pragma unroll
        for (int u = 0; u < UNROLL; ++u) {
            I[u] = p[(size_t)(t + u) * NVEC];
        }
#pragma unroll
        for (int u = 0; u < UNROLL; ++u) {
            f4 c = I[u];
            // reference order: V + alpha*((V_RESET - V) + I), V_RESET = 0
            vx = vx + alpha * (c.x - vx);
            vy = vy + alpha * (c.y - vy);
            vz = vz + alpha * (c.z - vz);
            vw = vw + alpha * (c.w - vw);
            f4 s;
            s.x = (vx >= vth) ? 1.0f : 0.0f;
            s.y = (vy >= vth) ? 1.0f : 0.0f;
            s.z = (vz >= vth) ? 1.0f : 0.0f;
            s.w = (vw >= vth) ? 1.0f : 0.0f;
            vx = (vx >= vth) ? 0.0f : vx;
            vy = (vy >= vth) ? 0.0f : vy;
            vz = (vz >= vth) ? 0.0f : vz;
            vw = (vw >= vth) ? 0.0f : vw;
            __builtin_nontemporal_store(s, q + (size_t)(t + u) * NVEC);
        }
    }
}

extern "C" void kernel_launch(void* const* d_in, const int* in_sizes, int n_in,
                              void* d_out, int out_size, void* d_ws, size_t ws_size,
                              hipStream_t stream) {
    const f4* in = (const f4*)d_in[0];
    f4* out = (f4*)d_out;
    lif_kernel<<<NVEC / BLOCK, BLOCK, 0, stream>>>(in, out);
}

// Round 2
// 426.995 us; speedup vs baseline: 1.1122x; 1.1122x over previous
//
#include <hip/hip_runtime.h>

// LIF recurrence: V = V + alpha*(I - V); spike = V>=1.0; V=0 on spike.
// N=65536 neurons (parallel), T=1024 steps (sequential per neuron).
// HBM stream: 256 MB read + 256 MB write (reads partially L3-absorbed).
//
// R1 changes vs R0:
//  - scalar f32 per thread (65536 threads, 4 waves/CU instead of 1) for TLP
//  - double-buffered prefetch: next batch's loads issue BEFORE current
//    batch's stores, so vmcnt in-order retirement never forces a store drain
//    on the load-wait path (R0 serialized on exactly that).

#define T_STEPS 1024
#define N NUM_NEURONS
#define NUM_NEURONS 65536
#define BLOCK 256
#define U 16   // loads in flight per wave; keeps worst-case outstanding vmem < 64

__global__ __launch_bounds__(BLOCK) void lif_kernel(const float* __restrict__ in,
                                                    float* __restrict__ out) {
    const int gid = blockIdx.x * BLOCK + threadIdx.x;  // [0, 65536)
    constexpr float alpha = 0.05f;  // DT/TAU = 1/20
    constexpr float vth = 1.0f;

    float V = 0.0f;  // V_RESET = 0
    const float* __restrict__ p = in + gid;
    float* __restrict__ q = out + gid;

    float I[U], J[U];

    // prologue: load first batch
#pragma unroll
    for (int u = 0; u < U; ++u) I[u] = p[(size_t)u * N];

    for (int t = 0; t < T_STEPS - U; t += U) {
        // prefetch batch t+U FIRST (program order before this batch's stores)
#pragma unroll
        for (int u = 0; u < U; ++u) J[u] = p[(size_t)(t + U + u) * N];
        // compute + store batch t
#pragma unroll
        for (int u = 0; u < U; ++u) {
            V = V + alpha * (I[u] - V);  // reference order, V_RESET = 0
            float s = (V >= vth) ? 1.0f : 0.0f;
            V = (V >= vth) ? 0.0f : V;
            __builtin_nontemporal_store(s, q + (size_t)(t + u) * N);
        }
#pragma unroll
        for (int u = 0; u < U; ++u) I[u] = J[u];
    }

    // epilogue: last batch (t = T_STEPS - U)
#pragma unroll
    for (int u = 0; u < U; ++u) {
        V = V + alpha * (I[u] - V);
        float s = (V >= vth) ? 1.0f : 0.0f;
        V = (V >= vth) ? 0.0f : V;
        __builtin_nontemporal_store(s, q + (size_t)(T_STEPS - U + u) * N);
    }
}

extern "C" void kernel_launch(void* const* d_in, const int* in_sizes, int n_in,
                              void* d_out, int out_size, void* d_ws, size_t ws_size,
                              hipStream_t stream) {
    const float* in = (const float*)d_in[0];
    float* out = (float*)d_out;
    lif_kernel<<<NUM_NEURONS / BLOCK, BLOCK, 0, stream>>>(in, out);
}